// Round 1
// 754.957 us; speedup vs baseline: 1.2234x; 1.2234x over previous
//
#include <hip/hip_runtime.h>

typedef __attribute__((ext_vector_type(8))) _Float16 half8;
typedef __attribute__((ext_vector_type(4))) float f32x4;

#define MFMA16(a,b,c) __builtin_amdgcn_mfma_f32_16x16x32_f16(a, b, c, 0, 0, 0)

// ---------------- prep kernel ----------------
// ws layout:
//   wqkvT : [768][256] f16   @ 0        (393216 B)  row c = qkv output col, ordered
//           per head h: [q_h(32) | k_h(32) | v_h(32)]; SCALE folded into q part
//   wpT   : [256][256] f16   @ 393216   (131072 B)  wpT[n][k] = wp[k][n]
//   bqkv  : [768] f32        @ 524288   (3072 B)    same col order, SCALE folded
//   biasg : [8][64][64] f32  @ 527360   (131072 B)  rpb_table[rel_idx[r][c]][h]
// total 658432 B
__global__ void prep_kernel(const float* __restrict__ wq, const float* __restrict__ bq,
                            const float* __restrict__ wkv, const float* __restrict__ bkv,
                            const float* __restrict__ wp, const float* __restrict__ rpb,
                            const int* __restrict__ rel,
                            _Float16* __restrict__ wqkvT, _Float16* __restrict__ wpT,
                            float* __restrict__ bqkv, float* __restrict__ biasg)
{
    int idx = blockIdx.x * 256 + threadIdx.x;
    const float scale = 0.17677669529663687f;  // 32^-0.5
    if (idx < 196608) {
        int c = idx >> 8, k = idx & 255;
        int h = c / 96, r = c % 96;
        float v;
        if (r < 32)      v = wq[k*256 + h*32 + r] * scale;
        else if (r < 64) v = wkv[k*512 + h*32 + (r-32)];
        else             v = wkv[k*512 + 256 + h*32 + (r-64)];
        wqkvT[c*256 + k] = (_Float16)v;
    } else if (idx < 262144) {
        int i = idx - 196608;
        int n = i >> 8, k = i & 255;
        wpT[i] = (_Float16)wp[k*256 + n];
    } else if (idx < 262912) {
        int c = idx - 262144;
        int h = c / 96, r = c % 96;
        float v;
        if (r < 32)      v = bq[h*32 + r] * scale;
        else if (r < 64) v = bkv[h*32 + (r-32)];
        else             v = bkv[256 + h*32 + (r-64)];
        bqkv[c] = v;
    } else if (idx < 295680) {
        int i = idx - 262912;
        int h = i >> 12, rc = i & 4095;
        biasg[i] = rpb[rel[rc]*8 + h];
    }
}

// ---------------- main fused kernel ----------------
// 1 block = 1 window (4096 blocks), 256 threads = 4 waves.
// LDS: sx 33792 (reused as f32 out-staging), sq/sk 2x5120 each, sv 2x4608,
// sP 9216, sO 9216 (pair-wide: [token][hh*32+d]) -> 81920 B total = exactly
// 2 blocks/CU (2*81920 = 163840 = full 160 KiB).
// Barriers: 2 per pair (post-stageB, pre-stageD). Post-stageD barrier removed:
// stage D reads only sO; next stage B writes only sq/sk/sv; next sO write is
// behind next pair's sync1 -> no hazard.
__global__ __launch_bounds__(256, 2)
void attn_main(const float* __restrict__ x,
               const _Float16* __restrict__ wqkvT,
               const _Float16* __restrict__ wpT,
               const float* __restrict__ bqkv,
               const float* __restrict__ biasg,
               const float* __restrict__ bp,
               float* __restrict__ out)
{
    __shared__ _Float16 sx[64*264];     // x window f16; later reused as f32 [32][264] staging
    __shared__ _Float16 sq[2][64*40];   // q  [head_in_pair][token][d]
    __shared__ _Float16 sk[2][64*40];   // k  [head_in_pair][token][d]
    __shared__ _Float16 sv[2][32*72];   // v^T [head_in_pair][d][token]
    __shared__ _Float16 sP[64*72];      // softmax probs [query][key] (wave-private rows)
    __shared__ _Float16 sO[64*72];      // pair attention out [token][hh*32+d]

    const int tid  = threadIdx.x;
    const int w    = tid >> 6;
    const int lane = tid & 63;
    const int l15  = lane & 15;
    const int quad = lane >> 4;
    const int b    = blockIdx.x;

    const float* xb = x + (size_t)b * (64*256);

    // ---- stage A: x (fp32) -> LDS f16 ----
    #pragma unroll
    for (int i = 0; i < 16; ++i) {
        int c4  = i*256 + tid;          // float4 index
        int row = c4 >> 6;
        int col = (c4 & 63) << 2;
        float4 v = ((const float4*)xb)[c4];
        union { _Float16 h[4]; uint2 u2; } pk;
        pk.h[0] = (_Float16)v.x; pk.h[1] = (_Float16)v.y;
        pk.h[2] = (_Float16)v.z; pk.h[3] = (_Float16)v.w;
        *(uint2*)(&sx[row*264 + col]) = pk.u2;
    }

    // persistent out-proj accumulators: [m-tile][n-tile], cols 64*w..64*w+63
    f32x4 dacc[4][4];
    #pragma unroll
    for (int i = 0; i < 4; ++i)
        #pragma unroll
        for (int j = 0; j < 4; ++j)
            dacc[i][j] = (f32x4){0.f, 0.f, 0.f, 0.f};

    __syncthreads();

    for (int pair = 0; pair < 4; ++pair) {
        // ---- stage B: qkv = x @ Wqkv for heads 2*pair, 2*pair+1 ----
        // ks-outer: af loaded once per k-step, reused by all 3 nt (1/3 the LDS reads)
        f32x4 acc[3][4];
        #pragma unroll
        for (int nt = 0; nt < 3; ++nt)
            #pragma unroll
            for (int mt = 0; mt < 4; ++mt)
                acc[nt][mt] = (f32x4){0.f, 0.f, 0.f, 0.f};

        #pragma unroll
        for (int ks = 0; ks < 8; ++ks) {
            half8 af[4];
            #pragma unroll
            for (int mt = 0; mt < 4; ++mt)
                af[mt] = *(const half8*)&sx[(16*mt + l15)*264 + ks*32 + quad*8];
            #pragma unroll
            for (int nt = 0; nt < 3; ++nt) {
                int gcol = pair*192 + w*48 + nt*16 + l15;
                half8 bf = *(const half8*)(wqkvT + (size_t)gcol*256 + ks*32 + quad*8);
                #pragma unroll
                for (int mt = 0; mt < 4; ++mt)
                    acc[nt][mt] = MFMA16(af[mt], bf, acc[nt][mt]);
            }
        }
        #pragma unroll
        for (int nt = 0; nt < 3; ++nt) {
            int seg = w*48 + nt*16;             // 0..176, multiple of 16
            float bv = bqkv[pair*192 + seg + l15];
            int hs  = (seg >= 96) ? 1 : 0;      // head within pair
            int r   = seg - 96*hs;
            int ty  = r >> 5;                    // 0=q 1=k 2=v
            int ds_ = r & 31;                    // 0 or 16
            #pragma unroll
            for (int mt = 0; mt < 4; ++mt) {
                #pragma unroll
                for (int rg = 0; rg < 4; ++rg) {
                    _Float16 hv = (_Float16)(acc[nt][mt][rg] + bv);
                    int token = 16*mt + quad*4 + rg;
                    if (ty == 0)      sq[hs][token*40 + ds_ + l15] = hv;
                    else if (ty == 1) sk[hs][token*40 + ds_ + l15] = hv;
                    else              sv[hs][(ds_ + l15)*72 + token] = hv;
                }
            }
        }
        __syncthreads();   // sync1: qkv visible to all waves

        for (int hh = 0; hh < 2; ++hh) {
            int h = pair*2 + hh;
            // ---- bias prefetch (L2) before QK so latency hides under MFMA ----
            float bb[4][4];
            #pragma unroll
            for (int rg = 0; rg < 4; ++rg) {
                const float* bg = biasg + ((h*64) + 16*w + quad*4 + rg)*64 + l15;
                bb[rg][0] = bg[0];  bb[rg][1] = bg[16];
                bb[rg][2] = bg[32]; bb[rg][3] = bg[48];
            }
            // ---- S = (q*scale) @ k^T ; wave w owns query rows 16w..16w+15 ----
            half8 aq = *(const half8*)&sq[hh][(16*w + l15)*40 + quad*8];
            f32x4 s[4];
            #pragma unroll
            for (int nt = 0; nt < 4; ++nt) {
                half8 bk = *(const half8*)&sk[hh][(16*nt + l15)*40 + quad*8];
                s[nt] = MFMA16(aq, bk, ((f32x4){0.f,0.f,0.f,0.f}));
            }
            // ---- bias + softmax (rows live in 16-lane groups: butterfly) ----
            float rinv[4];
            #pragma unroll
            for (int rg = 0; rg < 4; ++rg) {
                int row = quad*4 + rg;
                float t0 = s[0][rg] + bb[rg][0];
                float t1 = s[1][rg] + bb[rg][1];
                float t2 = s[2][rg] + bb[rg][2];
                float t3 = s[3][rg] + bb[rg][3];
                float m = fmaxf(fmaxf(t0, t1), fmaxf(t2, t3));
                #pragma unroll
                for (int d = 1; d < 16; d <<= 1)
                    m = fmaxf(m, __shfl_xor(m, d));
                float e0 = __expf(t0 - m), e1 = __expf(t1 - m);
                float e2 = __expf(t2 - m), e3 = __expf(t3 - m);
                float sum = e0 + e1 + e2 + e3;
                #pragma unroll
                for (int d = 1; d < 16; d <<= 1)
                    sum += __shfl_xor(sum, d);
                rinv[rg] = 1.0f / sum;
                int prow = (16*w + row)*72;
                sP[prow +  0 + l15] = (_Float16)e0;
                sP[prow + 16 + l15] = (_Float16)e1;
                sP[prow + 32 + l15] = (_Float16)e2;
                sP[prow + 48 + l15] = (_Float16)e3;
            }
            // ---- O = P @ V (P rows are wave-local; no barrier needed) ----
            f32x4 o[2];
            o[0] = o[1] = (f32x4){0.f,0.f,0.f,0.f};
            #pragma unroll
            for (int ks = 0; ks < 2; ++ks) {
                half8 ap = *(const half8*)&sP[(16*w + l15)*72 + ks*32 + quad*8];
                #pragma unroll
                for (int nt = 0; nt < 2; ++nt) {
                    half8 bv_ = *(const half8*)&sv[hh][(16*nt + l15)*72 + ks*32 + quad*8];
                    o[nt] = MFMA16(ap, bv_, o[nt]);
                }
            }
            // ---- scale by 1/l, stage into pair-wide sO (col = hh*32 + d) ----
            #pragma unroll
            for (int nt = 0; nt < 2; ++nt)
                #pragma unroll
                for (int rg = 0; rg < 4; ++rg)
                    sO[(16*w + quad*4 + rg)*72 + hh*32 + nt*16 + l15] =
                        (_Float16)(o[nt][rg] * rinv[rg]);
        }
        __syncthreads();   // sync2: sO (both heads) complete

        // ---- stage D (once per pair, K=64): dacc += O_pair @ wp[pair*64..+63, :]
        half8 aO[4][2];
        #pragma unroll
        for (int mt = 0; mt < 4; ++mt)
            #pragma unroll
            for (int ks = 0; ks < 2; ++ks)
                aO[mt][ks] = *(const half8*)&sO[(16*mt + l15)*72 + ks*32 + quad*8];
        #pragma unroll
        for (int nt = 0; nt < 4; ++nt) {
            #pragma unroll
            for (int ks = 0; ks < 2; ++ks) {
                half8 bw = *(const half8*)(wpT + (size_t)(64*w + 16*nt + l15)*256
                                           + pair*64 + ks*32 + quad*8);
                #pragma unroll
                for (int mt = 0; mt < 4; ++mt)
                    dacc[mt][nt] = MFMA16(aO[mt][ks], bw, dacc[mt][nt]);
            }
        }
        // no barrier: next stage B writes sq/sk/sv only (disjoint from sO);
        // next sO write is behind next sync1.
    }

    // ---- epilogue: stage dacc through sx region (f32) for full-line stores ----
    float* sxf = (float*)sx;                 // [32][264] f32 staging, 33792 B
    float* ob  = out + (size_t)b * (64*256);
    float4 bpv = ((const float4*)bp)[lane];  // cols 4*lane..4*lane+3
    #pragma unroll
    for (int chunk = 0; chunk < 2; ++chunk) {
        if (chunk) __syncthreads();          // chunk0 reads done before chunk1 writes
        #pragma unroll
        for (int mt2 = 0; mt2 < 2; ++mt2) {
            int mt = chunk*2 + mt2;
            #pragma unroll
            for (int nt = 0; nt < 4; ++nt)
                #pragma unroll
                for (int rg = 0; rg < 4; ++rg)
                    sxf[(16*mt2 + quad*4 + rg)*264 + 64*w + 16*nt + l15] = dacc[mt][nt][rg];
        }
        __syncthreads();
        #pragma unroll
        for (int i = 0; i < 8; ++i) {
            int row = i*4 + w;               // 0..31, one full row per instr
            float4 vv = *(const float4*)&sxf[row*264 + 4*lane];
            vv.x += bpv.x; vv.y += bpv.y; vv.z += bpv.z; vv.w += bpv.w;
            *(float4*)&ob[(size_t)(chunk*32 + row)*256 + 4*lane] = vv;
        }
    }
}

extern "C" void kernel_launch(void* const* d_in, const int* in_sizes, int n_in,
                              void* d_out, int out_size, void* d_ws, size_t ws_size,
                              hipStream_t stream)
{
    const float* x   = (const float*)d_in[0];
    const float* wq  = (const float*)d_in[1];
    const float* bq  = (const float*)d_in[2];
    const float* wkv = (const float*)d_in[3];
    const float* bkv = (const float*)d_in[4];
    const float* wp  = (const float*)d_in[5];
    const float* bp  = (const float*)d_in[6];
    const float* rpb = (const float*)d_in[7];
    const int*   rel = (const int*)d_in[8];

    char* ws = (char*)d_ws;
    _Float16* wqkvT = (_Float16*)(ws);
    _Float16* wpT   = (_Float16*)(ws + 393216);
    float*    bqkv  = (float*)(ws + 524288);
    float*    biasg = (float*)(ws + 527360);

    hipLaunchKernelGGL(prep_kernel, dim3(1155), dim3(256), 0, stream,
                       wq, bq, wkv, bkv, wp, rpb, rel, wqkvT, wpT, bqkv, biasg);
    hipLaunchKernelGGL(attn_main, dim3(4096), dim3(256), 0, stream,
                       x, wqkvT, wpT, bqkv, biasg, bp, (float*)d_out);
}

// Round 2
// 699.627 us; speedup vs baseline: 1.3201x; 1.0791x over previous
//
#include <hip/hip_runtime.h>

typedef __attribute__((ext_vector_type(8))) _Float16 half8;
typedef __attribute__((ext_vector_type(4))) float f32x4;

#define MFMA16(a,b,c) __builtin_amdgcn_mfma_f32_16x16x32_f16(a, b, c, 0, 0, 0)

// ---------------- prep kernel ----------------
// ws layout:
//   wqkvT : [768][256] f16   @ 0        (393216 B)  row c = qkv output col, ordered
//           per head h: [q_h(32) | k_h(32) | v_h(32)]; SCALE folded into q part
//   wpT   : [256][256] f16   @ 393216   (131072 B)  wpT[n][k] = wp[k][n]
//   bqkv  : [768] f32        @ 524288   (3072 B)    same col order, SCALE folded
//   biasg : [8][64][64] f32  @ 527360   (131072 B)  rpb_table[rel_idx[r][c]][h]
// total 658432 B
__global__ void prep_kernel(const float* __restrict__ wq, const float* __restrict__ bq,
                            const float* __restrict__ wkv, const float* __restrict__ bkv,
                            const float* __restrict__ wp, const float* __restrict__ rpb,
                            const int* __restrict__ rel,
                            _Float16* __restrict__ wqkvT, _Float16* __restrict__ wpT,
                            float* __restrict__ bqkv, float* __restrict__ biasg)
{
    int idx = blockIdx.x * 256 + threadIdx.x;
    const float scale = 0.17677669529663687f;  // 32^-0.5
    if (idx < 196608) {
        int c = idx >> 8, k = idx & 255;
        int h = c / 96, r = c % 96;
        float v;
        if (r < 32)      v = wq[k*256 + h*32 + r] * scale;
        else if (r < 64) v = wkv[k*512 + h*32 + (r-32)];
        else             v = wkv[k*512 + 256 + h*32 + (r-64)];
        wqkvT[c*256 + k] = (_Float16)v;
    } else if (idx < 262144) {
        int i = idx - 196608;
        int n = i >> 8, k = i & 255;
        wpT[i] = (_Float16)wp[k*256 + n];
    } else if (idx < 262912) {
        int c = idx - 262144;
        int h = c / 96, r = c % 96;
        float v;
        if (r < 32)      v = bq[h*32 + r] * scale;
        else if (r < 64) v = bkv[h*32 + (r-32)];
        else             v = bkv[256 + h*32 + (r-64)];
        bqkv[c] = v;
    } else if (idx < 295680) {
        int i = idx - 262912;
        int h = i >> 12, rc = i & 4095;
        biasg[i] = rpb[rel[rc]*8 + h];
    }
}

// ---------------- main fused kernel ----------------
// 1 block = 1 window (4096 blocks), 256 threads = 4 waves.
// All LDS writes are b64 (MFMA operand order chosen per-stage so the D layout
// has 4 contiguous elements per lane along the LDS-contiguous dim):
//   stage B q/k: MFMA(W, X)  -> lane holds (token, 4 chans)  -> b64 into [tok][ch]
//   stage B v  : MFMA(X, W)  -> lane holds (chan, 4 tokens)  -> b64 into [ch][tok]
//   QK^T       : MFMA(K, Q)  -> S^T: lane holds one query's keys -> in-lane softmax
//                (only 2+2 shfl_xor across quads), rinv folded into P, b64 P writes
//   PV         : MFMA(V, P)  -> lane holds (query, 4 chans)  -> b64 into sO
// LDS 81920 B -> 2 blocks/CU.
__global__ __launch_bounds__(256, 2)
void attn_main(const float* __restrict__ x,
               const _Float16* __restrict__ wqkvT,
               const _Float16* __restrict__ wpT,
               const float* __restrict__ bqkv,
               const float* __restrict__ biasg,
               const float* __restrict__ bp,
               float* __restrict__ out)
{
    __shared__ _Float16 sx[64*264];     // x window f16; later reused as f32 [32][264] staging
    __shared__ _Float16 sq[2][64*40];   // q  [head_in_pair][token][d]
    __shared__ _Float16 sk[2][64*40];   // k  [head_in_pair][token][d]
    __shared__ _Float16 sv[2][32*72];   // v^T [head_in_pair][d][token]
    __shared__ _Float16 sP[64*72];      // P' (pre-scaled probs) [query][key], wave-private rows
    __shared__ _Float16 sO[64*72];      // pair attention out [token][hh*32+d]

    const int tid  = threadIdx.x;
    const int w    = tid >> 6;
    const int lane = tid & 63;
    const int l15  = lane & 15;
    const int quad = lane >> 4;
    const int b    = blockIdx.x;

    const float* xb = x + (size_t)b * (64*256);

    // ---- stage A: x (fp32) -> LDS f16 ----
    #pragma unroll
    for (int i = 0; i < 16; ++i) {
        int c4  = i*256 + tid;          // float4 index
        int row = c4 >> 6;
        int col = (c4 & 63) << 2;
        float4 v = ((const float4*)xb)[c4];
        union { _Float16 h[4]; uint2 u2; } pk;
        pk.h[0] = (_Float16)v.x; pk.h[1] = (_Float16)v.y;
        pk.h[2] = (_Float16)v.z; pk.h[3] = (_Float16)v.w;
        *(uint2*)(&sx[row*264 + col]) = pk.u2;
    }

    // persistent out-proj accumulators: [m-tile][n-tile], cols 64*w..64*w+63
    f32x4 dacc[4][4];
    #pragma unroll
    for (int i = 0; i < 4; ++i)
        #pragma unroll
        for (int j = 0; j < 4; ++j)
            dacc[i][j] = (f32x4){0.f, 0.f, 0.f, 0.f};

    const bool wodd = (w & 1);          // wave-uniform

    __syncthreads();

    for (int pair = 0; pair < 4; ++pair) {
        // ---- stage B: qkv = x @ Wqkv for heads 2*pair, 2*pair+1 ----
        // wave w owns output cols [w*48, w*48+48); segment types:
        //   w even: (q, q, k)  -> all swapped-order MFMA
        //   w odd : (k, v, v)  -> nt0 swapped, nt1/nt2 normal
        f32x4 acc[3][4];
        #pragma unroll
        for (int nt = 0; nt < 3; ++nt)
            #pragma unroll
            for (int mt = 0; mt < 4; ++mt)
                acc[nt][mt] = (f32x4){0.f, 0.f, 0.f, 0.f};

        #pragma unroll
        for (int ks = 0; ks < 8; ++ks) {
            half8 af[4];
            #pragma unroll
            for (int mt = 0; mt < 4; ++mt)
                af[mt] = *(const half8*)&sx[(16*mt + l15)*264 + ks*32 + quad*8];
            half8 bf[3];
            #pragma unroll
            for (int nt = 0; nt < 3; ++nt) {
                int gcol = pair*192 + w*48 + nt*16 + l15;
                bf[nt] = *(const half8*)(wqkvT + (size_t)gcol*256 + ks*32 + quad*8);
            }
            if (!wodd) {
                #pragma unroll
                for (int nt = 0; nt < 3; ++nt)
                    #pragma unroll
                    for (int mt = 0; mt < 4; ++mt)
                        acc[nt][mt] = MFMA16(bf[nt], af[mt], acc[nt][mt]);
            } else {
                #pragma unroll
                for (int mt = 0; mt < 4; ++mt)
                    acc[0][mt] = MFMA16(bf[0], af[mt], acc[0][mt]);
                #pragma unroll
                for (int nt = 1; nt < 3; ++nt)
                    #pragma unroll
                    for (int mt = 0; mt < 4; ++mt)
                        acc[nt][mt] = MFMA16(af[mt], bf[nt], acc[nt][mt]);
            }
        }

        // ---- writeback: all b64 ----
        if (!wodd) {
            // swapped: lane holds (token = 16mt+l15, channels seg+4*quad+rg)
            #pragma unroll
            for (int nt = 0; nt < 3; ++nt) {
                int seg = w*48 + nt*16;
                int hs  = (seg >= 96) ? 1 : 0;
                int r   = seg - 96*hs;
                int ty  = r >> 5;                // 0,0,1 for w even
                int ds_ = (r & 31) + 4*quad;
                float4 bv4 = *(const float4*)(bqkv + pair*192 + seg + 4*quad);
                _Float16* dst = (ty == 0) ? sq[hs] : sk[hs];
                #pragma unroll
                for (int mt = 0; mt < 4; ++mt) {
                    union { _Float16 h[4]; uint2 u2; } pk;
                    pk.h[0] = (_Float16)(acc[nt][mt][0] + bv4.x);
                    pk.h[1] = (_Float16)(acc[nt][mt][1] + bv4.y);
                    pk.h[2] = (_Float16)(acc[nt][mt][2] + bv4.z);
                    pk.h[3] = (_Float16)(acc[nt][mt][3] + bv4.w);
                    *(uint2*)&dst[(16*mt + l15)*40 + ds_] = pk.u2;
                }
            }
        } else {
            {   // nt = 0: k segment, swapped
                int seg = w*48;                  // 48 or 144
                int hs  = (seg >= 96) ? 1 : 0;
                int ds_ = ((seg - 96*hs) & 31) + 4*quad;   // 16 + 4*quad
                float4 bv4 = *(const float4*)(bqkv + pair*192 + seg + 4*quad);
                #pragma unroll
                for (int mt = 0; mt < 4; ++mt) {
                    union { _Float16 h[4]; uint2 u2; } pk;
                    pk.h[0] = (_Float16)(acc[0][mt][0] + bv4.x);
                    pk.h[1] = (_Float16)(acc[0][mt][1] + bv4.y);
                    pk.h[2] = (_Float16)(acc[0][mt][2] + bv4.z);
                    pk.h[3] = (_Float16)(acc[0][mt][3] + bv4.w);
                    *(uint2*)&sk[hs][(16*mt + l15)*40 + ds_] = pk.u2;
                }
            }
            // nt = 1,2: v segments, normal order: lane holds (chan = ds_+l15, tokens 16mt+4quad+rg)
            #pragma unroll
            for (int nt = 1; nt < 3; ++nt) {
                int seg = w*48 + nt*16;          // 64,80 or 160,176
                int hs  = (seg >= 96) ? 1 : 0;
                int ds_ = (seg - 96*hs) & 31;    // 0 or 16
                float bv = bqkv[pair*192 + seg + l15];
                #pragma unroll
                for (int mt = 0; mt < 4; ++mt) {
                    union { _Float16 h[4]; uint2 u2; } pk;
                    pk.h[0] = (_Float16)(acc[nt][mt][0] + bv);
                    pk.h[1] = (_Float16)(acc[nt][mt][1] + bv);
                    pk.h[2] = (_Float16)(acc[nt][mt][2] + bv);
                    pk.h[3] = (_Float16)(acc[nt][mt][3] + bv);
                    *(uint2*)&sv[hs][(ds_ + l15)*72 + 16*mt + 4*quad] = pk.u2;
                }
            }
        }
        __syncthreads();   // sync1: qkv visible to all waves

        for (int hh = 0; hh < 2; ++hh) {
            int h = pair*2 + hh;
            // ---- bias prefetch: 4 float4, query = 16w+l15, keys 16nt+4quad..+3 ----
            const float* bgq = biasg + ((h*64) + 16*w + l15)*64 + 4*quad;
            float4 bb[4];
            #pragma unroll
            for (int nt = 0; nt < 4; ++nt)
                bb[nt] = *(const float4*)(bgq + 16*nt);

            // ---- S^T = K @ Q^T : lane holds (query = 16w+l15, keys 16nt+4quad+rg) ----
            half8 aq = *(const half8*)&sq[hh][(16*w + l15)*40 + quad*8];
            f32x4 s[4];
            #pragma unroll
            for (int nt = 0; nt < 4; ++nt) {
                half8 bk = *(const half8*)&sk[hh][(16*nt + l15)*40 + quad*8];
                s[nt] = MFMA16(bk, aq, ((f32x4){0.f,0.f,0.f,0.f}));
            }

            // ---- in-lane softmax over this lane's 16 keys + 2-step quad reduce ----
            float t[4][4];
            #pragma unroll
            for (int nt = 0; nt < 4; ++nt) {
                t[nt][0] = s[nt][0] + bb[nt].x;
                t[nt][1] = s[nt][1] + bb[nt].y;
                t[nt][2] = s[nt][2] + bb[nt].z;
                t[nt][3] = s[nt][3] + bb[nt].w;
            }
            float mx = t[0][0];
            #pragma unroll
            for (int nt = 0; nt < 4; ++nt)
                #pragma unroll
                for (int rg = 0; rg < 4; ++rg)
                    mx = fmaxf(mx, t[nt][rg]);
            mx = fmaxf(mx, __shfl_xor(mx, 16));
            mx = fmaxf(mx, __shfl_xor(mx, 32));
            float e[4][4];
            float sm = 0.f;
            #pragma unroll
            for (int nt = 0; nt < 4; ++nt)
                #pragma unroll
                for (int rg = 0; rg < 4; ++rg) {
                    e[nt][rg] = __expf(t[nt][rg] - mx);
                    sm += e[nt][rg];
                }
            sm += __shfl_xor(sm, 16);
            sm += __shfl_xor(sm, 32);
            float rinv = 1.0f / sm;

            // ---- P' = e * rinv, b64 writes to wave-private rows ----
            int prow = (16*w + l15)*72;
            #pragma unroll
            for (int nt = 0; nt < 4; ++nt) {
                union { _Float16 h[4]; uint2 u2; } pk;
                pk.h[0] = (_Float16)(e[nt][0] * rinv);
                pk.h[1] = (_Float16)(e[nt][1] * rinv);
                pk.h[2] = (_Float16)(e[nt][2] * rinv);
                pk.h[3] = (_Float16)(e[nt][3] * rinv);
                *(uint2*)&sP[prow + 16*nt + 4*quad] = pk.u2;
            }

            // ---- O^T = V^T @ P'^T : lane holds (query = 16w+l15, chans 16nt+4quad+rg) ----
            f32x4 o[2];
            o[0] = o[1] = (f32x4){0.f,0.f,0.f,0.f};
            #pragma unroll
            for (int ks = 0; ks < 2; ++ks) {
                half8 ap = *(const half8*)&sP[prow + ks*32 + quad*8];
                #pragma unroll
                for (int nt = 0; nt < 2; ++nt) {
                    half8 bv_ = *(const half8*)&sv[hh][(16*nt + l15)*72 + ks*32 + quad*8];
                    o[nt] = MFMA16(bv_, ap, o[nt]);
                }
            }
            // ---- stage into pair-wide sO: b64, no scaling needed ----
            #pragma unroll
            for (int nt = 0; nt < 2; ++nt) {
                union { _Float16 h[4]; uint2 u2; } pk;
                pk.h[0] = (_Float16)o[nt][0];
                pk.h[1] = (_Float16)o[nt][1];
                pk.h[2] = (_Float16)o[nt][2];
                pk.h[3] = (_Float16)o[nt][3];
                *(uint2*)&sO[(16*w + l15)*72 + hh*32 + 16*nt + 4*quad] = pk.u2;
            }
        }
        __syncthreads();   // sync2: sO (both heads) complete

        // ---- stage D (once per pair, K=64): dacc += O_pair @ wp[pair*64..+63, :]
        half8 aO[4][2];
        #pragma unroll
        for (int mt = 0; mt < 4; ++mt)
            #pragma unroll
            for (int ks = 0; ks < 2; ++ks)
                aO[mt][ks] = *(const half8*)&sO[(16*mt + l15)*72 + ks*32 + quad*8];
        #pragma unroll
        for (int nt = 0; nt < 4; ++nt) {
            #pragma unroll
            for (int ks = 0; ks < 2; ++ks) {
                half8 bw = *(const half8*)(wpT + (size_t)(64*w + 16*nt + l15)*256
                                           + pair*64 + ks*32 + quad*8);
                #pragma unroll
                for (int mt = 0; mt < 4; ++mt)
                    dacc[mt][nt] = MFMA16(aO[mt][ks], bw, dacc[mt][nt]);
            }
        }
        // no barrier: next stage B writes sq/sk/sv only (disjoint from sO);
        // next sO write is behind next sync1.
    }

    // ---- epilogue: stage dacc through sx region (f32) for full-line stores ----
    float* sxf = (float*)sx;                 // [32][264] f32 staging, 33792 B
    float* ob  = out + (size_t)b * (64*256);
    float4 bpv = ((const float4*)bp)[lane];  // cols 4*lane..4*lane+3
    #pragma unroll
    for (int chunk = 0; chunk < 2; ++chunk) {
        if (chunk) __syncthreads();          // chunk0 reads done before chunk1 writes
        #pragma unroll
        for (int mt2 = 0; mt2 < 2; ++mt2) {
            int mt = chunk*2 + mt2;
            #pragma unroll
            for (int nt = 0; nt < 4; ++nt)
                #pragma unroll
                for (int rg = 0; rg < 4; ++rg)
                    sxf[(16*mt2 + quad*4 + rg)*264 + 64*w + 16*nt + l15] = dacc[mt][nt][rg];
        }
        __syncthreads();
        #pragma unroll
        for (int i = 0; i < 8; ++i) {
            int row = i*4 + w;               // 0..31, one full row per instr
            float4 vv = *(const float4*)&sxf[row*264 + 4*lane];
            vv.x += bpv.x; vv.y += bpv.y; vv.z += bpv.z; vv.w += bpv.w;
            *(float4*)&ob[(size_t)(chunk*32 + row)*256 + 4*lane] = vv;
        }
    }
}

extern "C" void kernel_launch(void* const* d_in, const int* in_sizes, int n_in,
                              void* d_out, int out_size, void* d_ws, size_t ws_size,
                              hipStream_t stream)
{
    const float* x   = (const float*)d_in[0];
    const float* wq  = (const float*)d_in[1];
    const float* bq  = (const float*)d_in[2];
    const float* wkv = (const float*)d_in[3];
    const float* bkv = (const float*)d_in[4];
    const float* wp  = (const float*)d_in[5];
    const float* bp  = (const float*)d_in[6];
    const float* rpb = (const float*)d_in[7];
    const int*   rel = (const int*)d_in[8];

    char* ws = (char*)d_ws;
    _Float16* wqkvT = (_Float16*)(ws);
    _Float16* wpT   = (_Float16*)(ws + 393216);
    float*    bqkv  = (float*)(ws + 524288);
    float*    biasg = (float*)(ws + 527360);

    hipLaunchKernelGGL(prep_kernel, dim3(1155), dim3(256), 0, stream,
                       wq, bq, wkv, bkv, wp, rpb, rel, wqkvT, wpT, bqkv, biasg);
    hipLaunchKernelGGL(attn_main, dim3(4096), dim3(256), 0, stream,
                       x, wqkvT, wpT, bqkv, biasg, bp, (float*)d_out);
}